// Round 1
// baseline (265.907 us; speedup 1.0000x reference)
//
#include <hip/hip_runtime.h>
#include <hip/hip_bf16.h>

#define NB 4
#define NH 8
#define NW 20
#define NL 256
#define ND 64
#define ROWGRPS 40  // 5120 rows / 128 per block

typedef __attribute__((ext_vector_type(8))) short bf16x8;
typedef __attribute__((ext_vector_type(4))) short short4v;
typedef __attribute__((ext_vector_type(4))) float f32x4;

static __device__ __forceinline__ short f2bf(float f) {
  __hip_bfloat16 h = __float2bfloat16(f);
  short s;
  __builtin_memcpy(&s, &h, 2);
  return s;
}
static __device__ __forceinline__ float bf2f(short s) {
  __hip_bfloat16 h;
  __builtin_memcpy(&h, &s, 2);
  return __bfloat162float(h);
}

// ---------------- stage 1: scores[b,h,w,l] = dot(q[b,h,w,:], k[b,h,l,:]) / 8
__global__ __launch_bounds__(256) void qk_scores_kernel(
    const float* __restrict__ q, const float* __restrict__ k,
    float* __restrict__ scores) {
  const int bid = blockIdx.x;
  const int w = bid % NW;
  const int bh = bid / NW;  // b*NH + h
  const int l = threadIdx.x;
  const float4* qrow = (const float4*)(q + ((long)bh * NW + w) * ND);
  const float4* krow = (const float4*)(k + ((long)bh * NL + l) * ND);
  float acc = 0.f;
#pragma unroll
  for (int j = 0; j < ND / 4; ++j) {
    float4 a = qrow[j];
    float4 c = krow[j];
    acc += a.x * c.x + a.y * c.y + a.z * c.z + a.w * c.w;
  }
  scores[((long)bh * NW + w) * NL + l] = acc * 0.125f;
}

// ---------------- stage 2: softmax(scores+bias) @ V via bf16x3 MFMA
__global__ __launch_bounds__(512, 4) void attn_kernel(
    const float* __restrict__ v, const float* __restrict__ bias,
    const float* __restrict__ scores, float* __restrict__ out) {
  // V^T staged as bf16 hi/lo, XOR-swizzled: byte ^= (d&7)<<4 within each row.
  __shared__ short sv_hi[NL * ND];  // 32 KiB
  __shared__ short sv_lo[NL * ND];  // 32 KiB

  const int t = threadIdx.x;
  const int bid = blockIdx.x;
  const int rg = bid % ROWGRPS;
  const int h = (bid / ROWGRPS) % NH;
  const int b = bid / (ROWGRPS * NH);

  // ---- stage V^T (hi/lo) into LDS ----
  {
    const int d = t & 63;
    const int kb = (t >> 6) * 4;  // 0..28 step 4
    const float* vp = v + ((long)(b * NH + h)) * NL * ND + d;
#pragma unroll
    for (int i = 0; i < 8; ++i) {
      const int k0 = kb + i * 32;
      float f0 = vp[(long)(k0 + 0) * ND];
      float f1 = vp[(long)(k0 + 1) * ND];
      float f2 = vp[(long)(k0 + 2) * ND];
      float f3 = vp[(long)(k0 + 3) * ND];
      short4v hi, lo;
      hi.x = f2bf(f0); lo.x = f2bf(f0 - bf2f(hi.x));
      hi.y = f2bf(f1); lo.y = f2bf(f1 - bf2f(hi.y));
      hi.z = f2bf(f2); lo.z = f2bf(f2 - bf2f(hi.z));
      hi.w = f2bf(f3); lo.w = f2bf(f3 - bf2f(hi.w));
      const int off = (d << 9) + ((k0 << 1) ^ ((d & 7) << 4));
      *(short4v*)((char*)sv_hi + off) = hi;
      *(short4v*)((char*)sv_lo + off) = lo;
    }
  }
  __syncthreads();

  const int wave = t >> 6;
  const int lane = t & 63;
  const int rl = lane & 15;   // A-frag row within tile / C col (=d offset)
  const int g = lane >> 4;    // k-chunk group
  const int r0 = rg * 128 + wave * 16;
  const int row = r0 + rl;    // global attention row (= l*NW + w)
  const int li = row / NW;
  const int wi = row % NW;

  const float* brow = bias + (((long)(b * NL + li) * NH + h) * NW + wi) * NL;
  const float* srow = scores + ((long)((b * NH + h) * NW + wi)) * NL;

  f32x4 acc[4];
#pragma unroll
  for (int dt = 0; dt < 4; ++dt) acc[dt] = (f32x4){0.f, 0.f, 0.f, 0.f};
  float den = 0.f;

  const char* hb = (const char*)sv_hi;
  const char* lb = (const char*)sv_lo;

#pragma unroll 2
  for (int s = 0; s < 8; ++s) {
    const int k0 = s * 32 + g * 8;
    float4 b0 = *(const float4*)(brow + k0);
    float4 b1 = *(const float4*)(brow + k0 + 4);
    float4 s0 = *(const float4*)(srow + k0);
    float4 s1 = *(const float4*)(srow + k0 + 4);
    float p[8];
    p[0] = __expf(b0.x + s0.x);
    p[1] = __expf(b0.y + s0.y);
    p[2] = __expf(b0.z + s0.z);
    p[3] = __expf(b0.w + s0.w);
    p[4] = __expf(b1.x + s1.x);
    p[5] = __expf(b1.y + s1.y);
    p[6] = __expf(b1.z + s1.z);
    p[7] = __expf(b1.w + s1.w);
    den += ((p[0] + p[1]) + (p[2] + p[3])) + ((p[4] + p[5]) + (p[6] + p[7]));
    bf16x8 phi, plo;
#pragma unroll
    for (int j = 0; j < 8; ++j) {
      short hj = f2bf(p[j]);
      phi[j] = hj;
      plo[j] = f2bf(p[j] - bf2f(hj));
    }
#pragma unroll
    for (int dt = 0; dt < 4; ++dt) {
      const int d = dt * 16 + rl;
      const int off = (d << 9) + ((k0 << 1) ^ ((d & 7) << 4));
      bf16x8 vh = *(const bf16x8*)(hb + off);
      bf16x8 vl = *(const bf16x8*)(lb + off);
      acc[dt] = __builtin_amdgcn_mfma_f32_16x16x32_bf16(phi, vh, acc[dt], 0, 0, 0);
      acc[dt] = __builtin_amdgcn_mfma_f32_16x16x32_bf16(phi, vl, acc[dt], 0, 0, 0);
      acc[dt] = __builtin_amdgcn_mfma_f32_16x16x32_bf16(plo, vh, acc[dt], 0, 0, 0);
    }
  }

  // row denominator: combine the 4 k-chunk groups of each row
  float dsum = den + __shfl_xor(den, 16);
  dsum += __shfl_xor(dsum, 32);

  // C layout: col = lane&15 (d), row = (lane>>4)*4 + i (attention row)
  float* ob = out + ((long)b * (NL * NW)) * (NH * ND) + h * ND + rl;
#pragma unroll
  for (int i = 0; i < 4; ++i) {
    const int crow = (lane >> 4) * 4 + i;
    const float rinv = 1.0f / __shfl(dsum, crow);  // lane 'crow' holds row crow's den
    float* op = ob + (long)(r0 + crow) * (NH * ND);
    op[0]  = acc[0][i] * rinv;
    op[16] = acc[1][i] * rinv;
    op[32] = acc[2][i] * rinv;
    op[48] = acc[3][i] * rinv;
  }
}

extern "C" void kernel_launch(void* const* d_in, const int* in_sizes, int n_in,
                              void* d_out, int out_size, void* d_ws, size_t ws_size,
                              hipStream_t stream) {
  (void)in_sizes; (void)n_in; (void)out_size; (void)ws_size;
  const float* q = (const float*)d_in[0];
  const float* k = (const float*)d_in[1];
  const float* v = (const float*)d_in[2];
  const float* bias = (const float*)d_in[3];
  float* out = (float*)d_out;
  float* scores = (float*)d_ws;  // needs NB*NH*NW*NL*4 = 655,360 B of scratch

  qk_scores_kernel<<<NB * NH * NW, NL, 0, stream>>>(q, k, scores);
  attn_kernel<<<NB * NH * ROWGRPS, 512, 0, stream>>>(v, bias, scores, out);
}